// Round 12
// baseline (789.936 us; speedup 1.0000x reference)
//
#include <hip/hip_runtime.h>
#include <math.h>

#define B_   64
#define T_   500
#define IN_  1024
#define G_   8
#define HG_  128
#define J3_  384   // 3*HG

typedef _Float16 half8 __attribute__((ext_vector_type(8)));
typedef _Float16 half4 __attribute__((ext_vector_type(4)));
typedef float    f32x4 __attribute__((ext_vector_type(4)));

// sigmoid(a) = rcp(1 + exp2(S_RZ*a)); tanh(p) = 2*rcp(1+exp2(S_N*p))-1.
// Scales folded into the f16 weights and bias seeds (no muls in gates).
#define S_RZ (-1.44269504f)
#define S_N  (-2.88539008f)

static __device__ __forceinline__ half8 cvt_half8_s(const float* p, float s) {
    const float4 a = *(const float4*)p;
    const float4 b = *(const float4*)(p + 4);
    half8 h;
    h[0]=(_Float16)(a.x*s); h[1]=(_Float16)(a.y*s); h[2]=(_Float16)(a.z*s); h[3]=(_Float16)(a.w*s);
    h[4]=(_Float16)(b.x*s); h[5]=(_Float16)(b.y*s); h[6]=(_Float16)(b.z*s); h[7]=(_Float16)(b.w*s);
    return h;
}

// opaque reg-to-reg barrier: prevents rematerialization of loop-invariant state
static __device__ __forceinline__ void pin_frag(half8& h) {
    f32x4 t = __builtin_bit_cast(f32x4, h);
    float a = t[0], b = t[1], c = t[2], d = t[3];
    asm volatile("" : "+v"(a), "+v"(b), "+v"(c), "+v"(d));
    t[0] = a; t[1] = b; t[2] = c; t[3] = d;
    h = __builtin_bit_cast(half8, t);
}
static __device__ __forceinline__ void pin_f32x4(f32x4& v) {
    float a = v[0], b = v[1], c = v[2], d = v[3];
    asm volatile("" : "+v"(a), "+v"(b), "+v"(c), "+v"(d));
    v[0] = a; v[1] = b; v[2] = c; v[3] = d;
}

// LDS-only barrier: orders ds ops across the workgroup WITHOUT draining vmcnt.
static __device__ __forceinline__ void barrier_lds_only() {
    asm volatile("s_waitcnt lgkmcnt(0)\n\ts_barrier" ::: "memory");
}

#define MFMA16(A,Bv,C) __builtin_amdgcn_mfma_f32_16x16x32_f16((A),(Bv),(C),0,0,0)

// ---------------------------------------------------------------------------
// Kernel 0: cast x (fp32) -> x16 (f16), one-shot, memory-bound (~30 us).
// ---------------------------------------------------------------------------
__global__ __launch_bounds__(256)
void cvt_x(const float* __restrict__ x, _Float16* __restrict__ x16)
{
    const size_t n4 = (size_t)B_ * T_ * IN_ / 4;
    const size_t stride = (size_t)gridDim.x * 256;
    for (size_t i = (size_t)blockIdx.x * 256 + threadIdx.x; i < n4; i += stride) {
        const float4 v = ((const float4*)x)[i];
        half4 h;
        h[0] = (_Float16)v.x; h[1] = (_Float16)v.y;
        h[2] = (_Float16)v.z; h[3] = (_Float16)v.w;
        ((half4*)x16)[i] = h;
    }
}

// ---------------------------------------------------------------------------
// Kernel 1 (structure G4 = round-11 chain + 2 blocks/CU for bubble-filling):
// 512 blocks x 512 thr (8 waves), ONE real sequence per block, replicated
// across all 16 MFMA columns (b = blk>>3, g = blk&7). Only lr==0 stores.
// Round-11 PMC: MfmaUtil 40 + VALUBusy 46 at 2 waves/SIMD in lockstep ->
// issue-bound with dependency bubbles. Two co-resident blocks per CU
// (launch_bounds(512,2), VGPR 100 <= 128) interleave phases and fill them.
// Per step: 4 hmem ds_read -> 12 x-MFMA (xa(t+1), bias-seeded C-in)
//           -> BX(t+2) reload -> 12 h-MFMA (2+2 split, xa(t)/bias C-in)
//           -> lane-local folded-scale gates -> swizzled h write
//           -> lgkmcnt-only barrier -> masked out store.
// ---------------------------------------------------------------------------
__global__ __launch_bounds__(512, 2)
void gru_fused(const float* __restrict__ Wih, const float* __restrict__ Whh,
               const float* __restrict__ bih, const float* __restrict__ bhh,
               const _Float16* __restrict__ x16, float* __restrict__ out)
{
    const int tid  = threadIdx.x;
    const int lane = tid & 63;
    const int w    = tid >> 6;        // wave 0..7 == j-tile
    const int lr   = lane & 15;       // MFMA col (all duplicates of one seq)
    const int hi   = lane >> 4;       // 0..3
    const int blk  = blockIdx.x;      // 0..511
    const int g    = blk & 7;         // == XCD
    const int b    = blk >> 3;        // 0..63: the ONE real sequence
    const int jl   = w * 16 + hi * 4; // this lane's j base

    __shared__ _Float16 hmem[2][16 * 128];   // 8 KB, swizzled

    // ---- persistent pinned fragments, gate scales folded in ----
    half8 aI[3][4], aH[3][4];
#pragma unroll
    for (int p = 0; p < 3; ++p)
#pragma unroll
        for (int kt = 0; kt < 4; ++kt) {
            const size_t roff = (size_t)(g * J3_ + p * 128 + w * 16 + lr) * HG_
                              + kt * 32 + hi * 8;
            const float s = (p == 2) ? S_N : S_RZ;
            aI[p][kt] = cvt_half8_s(Wih + roff, s);  pin_frag(aI[p][kt]);
            aH[p][kt] = cvt_half8_s(Whh + roff, s);  pin_frag(aH[p][kt]);
        }

    // ---- bias seeds (scaled): r,z fold bih+bhh into x-chain; n splits ----
    const float* bi = bih + g * J3_;
    const float* bh = bhh + g * J3_;
    f32x4 s0 = (*(const f32x4*)(bi + jl)       + *(const f32x4*)(bh + jl))       * S_RZ;
    f32x4 s1 = (*(const f32x4*)(bi + 128 + jl) + *(const f32x4*)(bh + 128 + jl)) * S_RZ;
    f32x4 s2 = (*(const f32x4*)(bi + 256 + jl)) * S_N;
    f32x4 bhn_s = (*(const f32x4*)(bh + 256 + jl)) * S_N;
    pin_f32x4(s0); pin_f32x4(s1); pin_f32x4(s2); pin_f32x4(bhn_s);

    // ---- h = 0 init ----
    f32x4 hreg = (f32x4){0.f, 0.f, 0.f, 0.f};
    {
        const int gi = (2 * w + (hi >> 1)) ^ (lr & 7);
        half4 z; z[0]=(_Float16)0.f; z[1]=(_Float16)0.f; z[2]=(_Float16)0.f; z[3]=(_Float16)0.f;
        *(half4*)&hmem[0][lr * 128 + gi * 8 + (hi & 1) * 4] = z;
    }

    const _Float16* xrow = x16 + (size_t)b * T_ * IN_ + g * HG_;   // + tau*IN_
    float*          orow = out + (size_t)b * T_ * IN_ + g * HG_;   // + tau*IN_

    // ---- prologue: bxB <- x(0), bxA <- x(1); xaA = xa(0) ----
    half8 bxA[4], bxB[4];
#pragma unroll
    for (int kt = 0; kt < 4; ++kt) bxB[kt] = *(const half8*)(xrow + kt * 32 + hi * 8);
#pragma unroll
    for (int kt = 0; kt < 4; ++kt) bxA[kt] = *(const half8*)(xrow + IN_ + kt * 32 + hi * 8);

    f32x4 xaA0 = s0, xaA1 = s1, xaA2 = s2;
#pragma unroll
    for (int kt = 0; kt < 4; ++kt) {
        xaA0 = MFMA16(aI[0][kt], bxB[kt], xaA0);
        xaA1 = MFMA16(aI[1][kt], bxB[kt], xaA1);
        xaA2 = MFMA16(aI[2][kt], bxB[kt], xaA2);
    }
    f32x4 xaB0, xaB1, xaB2;

    __syncthreads();   // once, outside the loop

#define GRU_STEP(TAU, BXc, BXn, xc0, xc1, xc2, xn0, xn1, xn2)                      \
    do {                                                                           \
        const int pb = (TAU) & 1;                                                  \
        /* 1. h B-frags (ds_read issued first; latency hidden under 2&3) */       \
        const half8 bf0 = *(const half8*)&hmem[pb][lr * 128 + (( 0 + hi) ^ (lr & 7)) * 8]; \
        const half8 bf1 = *(const half8*)&hmem[pb][lr * 128 + (( 4 + hi) ^ (lr & 7)) * 8]; \
        const half8 bf2 = *(const half8*)&hmem[pb][lr * 128 + (( 8 + hi) ^ (lr & 7)) * 8]; \
        const half8 bf3 = *(const half8*)&hmem[pb][lr * 128 + ((12 + hi) ^ (lr & 7)) * 8]; \
        /* 2. x-projection for TAU+1 (bias-seeded C-in; h-independent) */          \
        xn0 = s0; xn1 = s1; xn2 = s2;                                              \
        _Pragma("unroll")                                                          \
        for (int kt = 0; kt < 4; ++kt) {                                           \
            xn0 = MFMA16(aI[0][kt], BXc[kt], xn0);                                 \
            xn1 = MFMA16(aI[1][kt], BXc[kt], xn1);                                 \
            xn2 = MFMA16(aI[2][kt], BXc[kt], xn2);                                 \
        }                                                                          \
        /* 3. reload BXn <- x(TAU+2); stays in flight across barriers */           \
        {                                                                          \
            int tn = (TAU) + 2; if (tn > T_ - 1) tn = T_ - 1;                      \
            const _Float16* px = xrow + (size_t)tn * IN_;                          \
            _Pragma("unroll")                                                      \
            for (int kt = 0; kt < 4; ++kt)                                         \
                BXn[kt] = *(const half8*)(px + kt * 32 + hi * 8);                  \
        }                                                                          \
        /* 4. h-MFMA, 2+2 split chains; xa(t)/bias ride C-in (free adds) */        \
        f32x4 h0a = xc0, h1a = xc1, h2a = bhn_s;                                   \
        f32x4 h0b = (f32x4){0.f,0.f,0.f,0.f}, h1b = h0b, h2b = h0b;                \
        h0a = MFMA16(aH[0][0], bf0, h0a);                                          \
        h1a = MFMA16(aH[1][0], bf0, h1a);                                          \
        h2a = MFMA16(aH[2][0], bf0, h2a);                                          \
        h0b = MFMA16(aH[0][2], bf2, h0b);                                          \
        h1b = MFMA16(aH[1][2], bf2, h1b);                                          \
        h2b = MFMA16(aH[2][2], bf2, h2b);                                          \
        h0a = MFMA16(aH[0][1], bf1, h0a);                                          \
        h1a = MFMA16(aH[1][1], bf1, h1a);                                          \
        h2a = MFMA16(aH[2][1], bf1, h2a);                                          \
        h0b = MFMA16(aH[0][3], bf3, h0b);                                          \
        h1b = MFMA16(aH[1][3], bf3, h1b);                                          \
        h2b = MFMA16(aH[2][3], bf3, h2b);                                          \
        const f32x4 ar = h0a + h0b;   /* = S_RZ*(xr+hr+biases) */                  \
        const f32x4 az = h1a + h1b;                                                \
        const f32x4 an = h2a + h2b;   /* = S_N*(hn+bhn) */                         \
        /* 5. lane-local gates, folded scales (6 trans + 7 VALU per j) */          \
        f32x4 hnew;                                                                \
        _Pragma("unroll")                                                          \
        for (int r = 0; r < 4; ++r) {                                              \
            const float rg = __builtin_amdgcn_rcpf(1.f + __builtin_amdgcn_exp2f(ar[r])); \
            const float zg = __builtin_amdgcn_rcpf(1.f + __builtin_amdgcn_exp2f(az[r])); \
            const float pre = xc2[r] + rg * an[r];      /* = S_N*(xn + rg*hn) */   \
            const float th  = __builtin_fmaf(2.f,                                  \
                __builtin_amdgcn_rcpf(1.f + __builtin_amdgcn_exp2f(pre)), -1.f);   \
            hnew[r] = __builtin_fmaf(zg, hreg[r] - th, th);                        \
        }                                                                          \
        hreg = hnew;                                                               \
        /* 6. write h for next step (swizzled), lds-only barrier */                \
        {                                                                          \
            half4 hh;                                                              \
            hh[0]=(_Float16)hnew[0]; hh[1]=(_Float16)hnew[1];                      \
            hh[2]=(_Float16)hnew[2]; hh[3]=(_Float16)hnew[3];                      \
            const int gi = (2 * w + (hi >> 1)) ^ (lr & 7);                         \
            *(half4*)&hmem[pb ^ 1][lr * 128 + gi * 8 + (hi & 1) * 4] = hh;         \
        }                                                                          \
        barrier_lds_only();                                                        \
        /* 7. masked out store (cols >=1 are duplicates) */                        \
        if (lr == 0) *(f32x4*)(orow + (size_t)(TAU) * IN_ + jl) = hnew;            \
    } while (0)

    for (int t = 0; t < T_; t += 2) {
        GRU_STEP(t,     bxA, bxB, xaA0, xaA1, xaA2, xaB0, xaB1, xaB2);
        GRU_STEP(t + 1, bxB, bxA, xaB0, xaB1, xaB2, xaA0, xaA1, xaA2);
    }
#undef GRU_STEP
}

// ---------------------------------------------------------------------------
extern "C" void kernel_launch(void* const* d_in, const int* in_sizes, int n_in,
                              void* d_out, int out_size, void* d_ws, size_t ws_size,
                              hipStream_t stream) {
    (void)in_sizes; (void)n_in; (void)out_size; (void)ws_size;
    const float* x   = (const float*)d_in[0];
    const float* Wih = (const float*)d_in[1];
    const float* Whh = (const float*)d_in[2];
    const float* bih = (const float*)d_in[3];
    const float* bhh = (const float*)d_in[4];
    float* out = (float*)d_out;

    _Float16* x16 = (_Float16*)d_ws;    // 65.5 MB

    cvt_x<<<4096, 256, 0, stream>>>(x, x16);
    gru_fused<<<512, 512, 0, stream>>>(Wih, Whh, bih, bhh, x16, out);
}

// Round 13
// 756.703 us; speedup vs baseline: 1.0439x; 1.0439x over previous
//
#include <hip/hip_runtime.h>
#include <math.h>

#define B_   64
#define T_   500
#define IN_  1024
#define G_   8
#define HG_  128
#define J3_  384   // 3*HG

typedef _Float16 half8 __attribute__((ext_vector_type(8)));
typedef _Float16 half4 __attribute__((ext_vector_type(4)));
typedef float    f32x4 __attribute__((ext_vector_type(4)));

// sigmoid(a) = rcp(1 + exp2(S_RZ*a)); tanh(p) = 2*rcp(1+exp2(S_N*p))-1.
// Scales folded into the f16 weights / xp values / bias seeds.
#define S_RZ (-1.44269504f)
#define S_N  (-2.88539008f)

static __device__ __forceinline__ half8 cvt_half8(const float* p) {
    const float4 a = *(const float4*)p;
    const float4 b = *(const float4*)(p + 4);
    half8 h;
    h[0]=(_Float16)a.x; h[1]=(_Float16)a.y; h[2]=(_Float16)a.z; h[3]=(_Float16)a.w;
    h[4]=(_Float16)b.x; h[5]=(_Float16)b.y; h[6]=(_Float16)b.z; h[7]=(_Float16)b.w;
    return h;
}
static __device__ __forceinline__ half8 cvt_half8_s(const float* p, float s) {
    const float4 a = *(const float4*)p;
    const float4 b = *(const float4*)(p + 4);
    half8 h;
    h[0]=(_Float16)(a.x*s); h[1]=(_Float16)(a.y*s); h[2]=(_Float16)(a.z*s); h[3]=(_Float16)(a.w*s);
    h[4]=(_Float16)(b.x*s); h[5]=(_Float16)(b.y*s); h[6]=(_Float16)(b.z*s); h[7]=(_Float16)(b.w*s);
    return h;
}

// opaque reg-to-reg barrier: prevents rematerialization of loop-invariant state
static __device__ __forceinline__ void pin_frag(half8& h) {
    f32x4 t = __builtin_bit_cast(f32x4, h);
    float a = t[0], b = t[1], c = t[2], d = t[3];
    asm volatile("" : "+v"(a), "+v"(b), "+v"(c), "+v"(d));
    t[0] = a; t[1] = b; t[2] = c; t[3] = d;
    h = __builtin_bit_cast(half8, t);
}
static __device__ __forceinline__ void pin_f32x4(f32x4& v) {
    float a = v[0], b = v[1], c = v[2], d = v[3];
    asm volatile("" : "+v"(a), "+v"(b), "+v"(c), "+v"(d));
    v[0] = a; v[1] = b; v[2] = c; v[3] = d;
}

// LDS-only barrier: orders ds ops across the workgroup WITHOUT draining vmcnt.
static __device__ __forceinline__ void barrier_lds_only() {
    asm volatile("s_waitcnt lgkmcnt(0)\n\ts_barrier" ::: "memory");
}

#define MFMA16(A,Bv,C) __builtin_amdgcn_mfma_f32_16x16x32_f16((A),(Bv),(C),0,0,0)

// ---------------------------------------------------------------------------
// Kernel A: full-T input projection (MFMA), fp32 x in, f16 SCALED xp out.
//   xp[row*G+g][j] where row = t*64+b:
//     jb=0 (r): S_RZ*(x·Wr + bi_r + bh_r)
//     jb=1 (z): S_RZ*(x·Wz + bi_z + bh_z)
//     jb=2 (n): S_N *(x·Wn + bi_n)            (bh_n stays in the recurrence)
// 6000 blocks x 256 thr; K=128 resident; per-lane direct frag loads; output
// bounced through XOR-swizzled LDS for coalesced f16 stores. g == XCD.
// ---------------------------------------------------------------------------
__global__ __launch_bounds__(256, 2)
void gru_xproj(const float* __restrict__ x, const float* __restrict__ Wih,
               const float* __restrict__ bih, const float* __restrict__ bhh,
               _Float16* __restrict__ xp)
{
    __shared__ _Float16 cs[128 * 128];

    const int lin = blockIdx.x;
    const int g   = lin & 7;
    const int rem = lin >> 3;
    const int jb  = rem % 3;             // gate
    const int q   = rem / 3;             // row-block 0..249
    const int j0  = jb * 128;
    const int row0 = q * 128;
    const float s = (jb == 2) ? S_N : S_RZ;

    const int tid  = threadIdx.x;
    const int lane = tid & 63;
    const int w    = tid >> 6;
    const int wm   = w >> 1, wn = w & 1;
    const int lr   = lane & 15, hi = lane >> 4;

    const float* xbase[4];
#pragma unroll
    for (int mi = 0; mi < 4; ++mi) {
        const int row = row0 + wm * 64 + mi * 16 + lr;
        const int b   = row & 63;
        const int t   = row >> 6;
        xbase[mi] = x + ((size_t)b * T_ + t) * IN_ + g * HG_;
    }
    const float* wbase[4];
#pragma unroll
    for (int ni = 0; ni < 4; ++ni)
        wbase[ni] = Wih + (size_t)(g * J3_ + j0 + wn * 64 + ni * 16 + lr) * HG_;

    f32x4 acc[4][4];
#pragma unroll
    for (int mi = 0; mi < 4; ++mi)
#pragma unroll
        for (int ni = 0; ni < 4; ++ni) acc[mi][ni] = (f32x4){0.f, 0.f, 0.f, 0.f};

#pragma unroll
    for (int kt = 0; kt < 4; ++kt) {
        half8 af[4], bf[4];
#pragma unroll
        for (int mi = 0; mi < 4; ++mi) af[mi] = cvt_half8(xbase[mi] + kt * 32 + hi * 8);
#pragma unroll
        for (int ni = 0; ni < 4; ++ni) bf[ni] = cvt_half8_s(wbase[ni] + kt * 32 + hi * 8, s);
#pragma unroll
        for (int mi = 0; mi < 4; ++mi)
#pragma unroll
            for (int ni = 0; ni < 4; ++ni)
                acc[mi][ni] = MFMA16(af[mi], bf[ni], acc[mi][ni]);
    }

    // scaled, folded biases
    float bias_s[4];
#pragma unroll
    for (int ni = 0; ni < 4; ++ni) {
        const int j = g * J3_ + j0 + wn * 64 + ni * 16 + lr;
        bias_s[ni] = s * (bih[j] + ((jb < 2) ? bhh[j] : 0.f));
    }

#pragma unroll
    for (int mi = 0; mi < 4; ++mi)
#pragma unroll
        for (int ni = 0; ni < 4; ++ni)
#pragma unroll
            for (int r = 0; r < 4; ++r) {
                const int row  = wm * 64 + mi * 16 + hi * 4 + r;
                const int colb = (wn * 64 + ni * 16 + lr) * 2;
                const int addr = row * 256 + (colb ^ ((row & 7) << 4));
                *(_Float16*)((char*)cs + addr) = (_Float16)(acc[mi][ni][r] + bias_s[ni]);
            }
    __syncthreads();

#pragma unroll
    for (int sdx = 0; sdx < 8; ++sdx) {
        const int u   = sdx * 256 + tid;
        const int row = u >> 4;
        const int c16 = u & 15;
        const int addr = row * 256 + ((c16 * 16) ^ ((row & 7) << 4));
        const half8 v = *(const half8*)((const char*)cs + addr);
        *(half8*)(xp + ((size_t)(row0 + row) * G_ + g) * J3_ + j0 + c16 * 8) = v;
    }
}

// ---------------------------------------------------------------------------
// Kernel B (structure I): LEAN recurrence, 2 blocks/CU.
// 512 blocks x 512 thr (8 waves), 1 real sequence per block replicated
// across all 16 MFMA columns (b = blk>>3, g = blk&7 == XCD). lr==0 stores.
// Round-12 lesson: __launch_bounds__ 2nd arg is waves/EU; (512,4) => 4
// waves/EU => 2 co-resident 8-wave blocks per CU, reg cap 128. Dropping the
// x-projection (aI, 48 regs) is what makes the kernel fit (~104 total).
// Two independent barrier domains per CU interleave phases -> fill bubbles.
// Per step: 4 hmem ds_read -> 12 h-MFMA (2+2 split; acc2 C-in = S_N*bh_n)
//   -> gates (xa from xp added at gate time; loads 2 steps ahead ~1000cy
//   slack > HBM 900cy) -> swizzled h write -> issue xa(t+2) -> lds-only
//   barrier -> masked out store.
// ---------------------------------------------------------------------------
__global__ __launch_bounds__(512, 4)
void gru_rec(const float* __restrict__ Whh, const float* __restrict__ bhh,
             const _Float16* __restrict__ xp, float* __restrict__ out)
{
    const int tid  = threadIdx.x;
    const int lane = tid & 63;
    const int w    = tid >> 6;        // wave 0..7 == j-tile
    const int lr   = lane & 15;       // MFMA col (all duplicates)
    const int hi   = lane >> 4;       // 0..3
    const int blk  = blockIdx.x;      // 0..511
    const int g    = blk & 7;         // == XCD
    const int b    = blk >> 3;        // the ONE real sequence
    const int jl   = w * 16 + hi * 4;

    __shared__ _Float16 hmem[2][16 * 128];   // 8 KB, swizzled

    // persistent pinned W_hh fragments (scales folded): 48 VGPR
    half8 aH[3][4];
#pragma unroll
    for (int p = 0; p < 3; ++p)
#pragma unroll
        for (int kt = 0; kt < 4; ++kt) {
            aH[p][kt] = cvt_half8_s(
                Whh + (size_t)(g * J3_ + p * 128 + w * 16 + lr) * HG_ + kt * 32 + hi * 8,
                (p == 2) ? S_N : S_RZ);
            pin_frag(aH[p][kt]);
        }
    f32x4 bhn_s = (*(const f32x4*)(bhh + g * J3_ + 256 + jl)) * S_N;
    pin_f32x4(bhn_s);

    // h = 0 init
    f32x4 hreg = (f32x4){0.f, 0.f, 0.f, 0.f};
    const int gi = (2 * w + (hi >> 1)) ^ (lr & 7);
    {
        half4 z; z[0]=(_Float16)0.f; z[1]=(_Float16)0.f; z[2]=(_Float16)0.f; z[3]=(_Float16)0.f;
        *(half4*)&hmem[0][lr * 128 + gi * 8 + (hi & 1) * 4] = z;
    }

    // xp addressing: row = t*64+b; elem = (row*8+g)*384 + gate*128 + jl
    const size_t tstride = (size_t)64 * G_ * J3_;                  // per-t elems
    const _Float16* xpb = xp + ((size_t)b * G_ + g) * J3_ + jl;    // + t*tstride + gate*128
    float* orow = out + (size_t)b * T_ * IN_ + g * HG_ + jl;       // + t*IN_

    // prologue: X <- xa(0), Y <- xa(1)
    half4 X0 = *(const half4*)(xpb);
    half4 X1 = *(const half4*)(xpb + 128);
    half4 X2 = *(const half4*)(xpb + 256);
    half4 Y0 = *(const half4*)(xpb + tstride);
    half4 Y1 = *(const half4*)(xpb + tstride + 128);
    half4 Y2 = *(const half4*)(xpb + tstride + 256);

    __syncthreads();

#define REC_STEP(TAU, C0, C1, C2)                                                  \
    do {                                                                           \
        const int pb = (TAU) & 1;                                                  \
        /* 1. h B-frags */                                                         \
        const half8 bf0 = *(const half8*)&hmem[pb][lr * 128 + (( 0 + hi) ^ (lr & 7)) * 8]; \
        const half8 bf1 = *(const half8*)&hmem[pb][lr * 128 + (( 4 + hi) ^ (lr & 7)) * 8]; \
        const half8 bf2 = *(const half8*)&hmem[pb][lr * 128 + (( 8 + hi) ^ (lr & 7)) * 8]; \
        const half8 bf3 = *(const half8*)&hmem[pb][lr * 128 + ((12 + hi) ^ (lr & 7)) * 8]; \
        /* 2. h-MFMA, 2+2 split; n-chain C-in seeded with S_N*bh_n */              \
        f32x4 h0a = (f32x4){0.f,0.f,0.f,0.f}, h1a = h0a, h0b = h0a, h1b = h0a, h2b = h0a; \
        f32x4 h2a = bhn_s;                                                         \
        h0a = MFMA16(aH[0][0], bf0, h0a);                                          \
        h1a = MFMA16(aH[1][0], bf0, h1a);                                          \
        h2a = MFMA16(aH[2][0], bf0, h2a);                                          \
        h0b = MFMA16(aH[0][2], bf2, h0b);                                          \
        h1b = MFMA16(aH[1][2], bf2, h1b);                                          \
        h2b = MFMA16(aH[2][2], bf2, h2b);                                          \
        h0a = MFMA16(aH[0][1], bf1, h0a);                                          \
        h1a = MFMA16(aH[1][1], bf1, h1a);                                          \
        h2a = MFMA16(aH[2][1], bf1, h2a);                                          \
        h0b = MFMA16(aH[0][3], bf3, h0b);                                          \
        h1b = MFMA16(aH[1][3], bf3, h1b);                                          \
        h2b = MFMA16(aH[2][3], bf3, h2b);                                          \
        const f32x4 ha0 = h0a + h0b;   /* S_RZ*(hr) */                             \
        const f32x4 ha1 = h1a + h1b;   /* S_RZ*(hz) */                             \
        const f32x4 ha2 = h2a + h2b;   /* S_N*(hn+bh_n) */                         \
        /* 3. gates: xa (preloaded 2 steps ago) added here, scales folded */       \
        f32x4 hnew;                                                                \
        _Pragma("unroll")                                                          \
        for (int r = 0; r < 4; ++r) {                                              \
            const float ar = (float)C0[r] + ha0[r];                                \
            const float az = (float)C1[r] + ha1[r];                                \
            const float rg = __builtin_amdgcn_rcpf(1.f + __builtin_amdgcn_exp2f(ar)); \
            const float zg = __builtin_amdgcn_rcpf(1.f + __builtin_amdgcn_exp2f(az)); \
            const float pre = (float)C2[r] + rg * ha2[r];                          \
            const float th  = __builtin_fmaf(2.f,                                  \
                __builtin_amdgcn_rcpf(1.f + __builtin_amdgcn_exp2f(pre)), -1.f);   \
            hnew[r] = __builtin_fmaf(zg, hreg[r] - th, th);                        \
        }                                                                          \
        hreg = hnew;                                                               \
        /* 4. write h (swizzled) */                                                \
        {                                                                          \
            half4 hh;                                                              \
            hh[0]=(_Float16)hnew[0]; hh[1]=(_Float16)hnew[1];                      \
            hh[2]=(_Float16)hnew[2]; hh[3]=(_Float16)hnew[3];                      \
            *(half4*)&hmem[pb ^ 1][lr * 128 + gi * 8 + (hi & 1) * 4] = hh;         \
        }                                                                          \
        /* 5. refill this step's buffer with xa(TAU+2); 2-step flight time */      \
        {                                                                          \
            int tn = (TAU) + 2; if (tn > T_ - 1) tn = T_ - 1;                      \
            const _Float16* px = xpb + (size_t)tn * tstride;                       \
            C0 = *(const half4*)(px);                                              \
            C1 = *(const half4*)(px + 128);                                        \
            C2 = *(const half4*)(px + 256);                                        \
        }                                                                          \
        barrier_lds_only();                                                        \
        /* 6. masked out store (cols >=1 are duplicates) */                        \
        if (lr == 0) *(f32x4*)(orow + (size_t)(TAU) * IN_) = hnew;                 \
    } while (0)

    for (int t = 0; t < T_; t += 2) {
        REC_STEP(t,     X0, X1, X2);
        REC_STEP(t + 1, Y0, Y1, Y2);
    }
#undef REC_STEP
}

// ---------------------------------------------------------------------------
extern "C" void kernel_launch(void* const* d_in, const int* in_sizes, int n_in,
                              void* d_out, int out_size, void* d_ws, size_t ws_size,
                              hipStream_t stream) {
    (void)in_sizes; (void)n_in; (void)out_size; (void)ws_size;
    const float* x   = (const float*)d_in[0];
    const float* Wih = (const float*)d_in[1];
    const float* Whh = (const float*)d_in[2];
    const float* bih = (const float*)d_in[3];
    const float* bhh = (const float*)d_in[4];
    float* out = (float*)d_out;

    _Float16* xp = (_Float16*)d_ws;   // 32000*8*384*2B = 196.6 MB (fits ws)

    gru_xproj<<<6000, 256, 0, stream>>>(x, Wih, bih, bhh, xp);
    gru_rec<<<512, 512, 0, stream>>>(Whh, bhh, xp, out);
}

// Round 14
// 364.072 us; speedup vs baseline: 2.1697x; 2.0784x over previous
//
#include <hip/hip_runtime.h>
#include <math.h>

#define B_   64
#define T_   500
#define IN_  1024
#define G_   8
#define HG_  128
#define J3_  384   // 3*HG

typedef _Float16 half8 __attribute__((ext_vector_type(8)));
typedef _Float16 half4 __attribute__((ext_vector_type(4)));
typedef float    f32x4 __attribute__((ext_vector_type(4)));

// sigmoid(a) = rcp(1 + exp2(S_RZ*a)); tanh(p) = 2*rcp(1+exp2(S_N*p))-1.
// Scales folded into the f16 weights and bias seeds (no muls in gates).
#define S_RZ (-1.44269504f)
#define S_N  (-2.88539008f)

static __device__ __forceinline__ half8 cvt_half8_s(const float* p, float s) {
    const float4 a = *(const float4*)p;
    const float4 b = *(const float4*)(p + 4);
    half8 h;
    h[0]=(_Float16)(a.x*s); h[1]=(_Float16)(a.y*s); h[2]=(_Float16)(a.z*s); h[3]=(_Float16)(a.w*s);
    h[4]=(_Float16)(b.x*s); h[5]=(_Float16)(b.y*s); h[6]=(_Float16)(b.z*s); h[7]=(_Float16)(b.w*s);
    return h;
}

// opaque reg-to-reg barrier: prevents rematerialization of loop-invariant state
static __device__ __forceinline__ void pin_frag(half8& h) {
    f32x4 t = __builtin_bit_cast(f32x4, h);
    float a = t[0], b = t[1], c = t[2], d = t[3];
    asm volatile("" : "+v"(a), "+v"(b), "+v"(c), "+v"(d));
    t[0] = a; t[1] = b; t[2] = c; t[3] = d;
    h = __builtin_bit_cast(half8, t);
}
static __device__ __forceinline__ void pin_f32x4(f32x4& v) {
    float a = v[0], b = v[1], c = v[2], d = v[3];
    asm volatile("" : "+v"(a), "+v"(b), "+v"(c), "+v"(d));
    v[0] = a; v[1] = b; v[2] = c; v[3] = d;
}

// LDS-only barrier: orders ds ops across the workgroup WITHOUT draining vmcnt.
static __device__ __forceinline__ void barrier_lds_only() {
    asm volatile("s_waitcnt lgkmcnt(0)\n\ts_barrier" ::: "memory");
}

#define MFMA16(A,Bv,C) __builtin_amdgcn_mfma_f32_16x16x32_f16((A),(Bv),(C),0,0,0)

// ---------------------------------------------------------------------------
// Kernel 0: cast x (fp32) -> x16 (f16), one-shot, memory-bound (~30 us).
// ---------------------------------------------------------------------------
__global__ __launch_bounds__(256)
void cvt_x(const float* __restrict__ x, _Float16* __restrict__ x16)
{
    const size_t n4 = (size_t)B_ * T_ * IN_ / 4;
    const size_t stride = (size_t)gridDim.x * 256;
    for (size_t i = (size_t)blockIdx.x * 256 + threadIdx.x; i < n4; i += stride) {
        const float4 v = ((const float4*)x)[i];
        half4 h;
        h[0] = (_Float16)v.x; h[1] = (_Float16)v.y;
        h[2] = (_Float16)v.z; h[3] = (_Float16)v.w;
        ((half4*)x16)[i] = h;
    }
}

// ---------------------------------------------------------------------------
// Kernel 1 (structure G5 = G3 + TIMESTEP-BATCHED x-projection):
// 256 blocks x 512 thr (8 waves), 2 real seqs/block (b = bp*2 + (lr&1)).
// Corrected HW model: one 16x16x32 f16 MFMA = ~19.4cy/SIMD; round-11's 24
// MFMA/step = 931cy/SIMD = 48% of the step. Half of those computed a
// 16-col-DUPLICATED x-projection. Fix: batch x-proj over time - B-cols =
// 8 timesteps x 2 seqs (all 16 cols real), run once per 8 steps
// (amortized 1.5 MFMA/step). Results go through LDS xmem (same-wave
// write/read: no barrier). Per step: 12 h-MFMA only, xa rides C-in.
// ---------------------------------------------------------------------------
__global__ __launch_bounds__(512, 1)
void gru_fused(const float* __restrict__ Wih, const float* __restrict__ Whh,
               const float* __restrict__ bih, const float* __restrict__ bhh,
               const _Float16* __restrict__ x16, float* __restrict__ out)
{
    const int tid  = threadIdx.x;
    const int lane = tid & 63;
    const int w    = tid >> 6;        // wave 0..7 == j-tile
    const int lr   = lane & 15;       // MFMA col
    const int hi   = lane >> 4;       // 0..3
    const int blk  = blockIdx.x;      // 0..255
    const int g    = blk & 7;         // == XCD
    const int bp   = blk >> 3;        // 0..31
    const int sq   = lr & 1;          // h-path: seq parity
    const int b    = bp * 2 + sq;
    const int jl   = w * 16 + hi * 4;

    __shared__ _Float16 hmem[2][16 * 128];   // 8 KB, swizzled
    __shared__ float    xmem[16][392];       // 24.5 KB: [col = ts*2+seq][gate*128 + j]

    // ---- persistent pinned fragments, gate scales folded in ----
    half8 aI[3][4], aH[3][4];
#pragma unroll
    for (int p = 0; p < 3; ++p)
#pragma unroll
        for (int kt = 0; kt < 4; ++kt) {
            const size_t roff = (size_t)(g * J3_ + p * 128 + w * 16 + lr) * HG_
                              + kt * 32 + hi * 8;
            const float s = (p == 2) ? S_N : S_RZ;
            aI[p][kt] = cvt_half8_s(Wih + roff, s);  pin_frag(aI[p][kt]);
            aH[p][kt] = cvt_half8_s(Whh + roff, s);  pin_frag(aH[p][kt]);
        }

    // ---- bias seeds (scaled): r,z fold bih+bhh into x-GEMM; n splits ----
    const float* bi = bih + g * J3_;
    const float* bh = bhh + g * J3_;
    f32x4 s0 = (*(const f32x4*)(bi + jl)       + *(const f32x4*)(bh + jl))       * S_RZ;
    f32x4 s1 = (*(const f32x4*)(bi + 128 + jl) + *(const f32x4*)(bh + 128 + jl)) * S_RZ;
    f32x4 s2 = (*(const f32x4*)(bi + 256 + jl)) * S_N;
    f32x4 bhn_s = (*(const f32x4*)(bh + 256 + jl)) * S_N;
    pin_f32x4(s0); pin_f32x4(s1); pin_f32x4(s2); pin_f32x4(bhn_s);

    // ---- h = 0 init ----
    f32x4 hreg = (f32x4){0.f, 0.f, 0.f, 0.f};
    const int gi = (2 * w + (hi >> 1)) ^ (lr & 7);
    {
        half4 z; z[0]=(_Float16)0.f; z[1]=(_Float16)0.f; z[2]=(_Float16)0.f; z[3]=(_Float16)0.f;
        *(half4*)&hmem[0][lr * 128 + gi * 8 + (hi & 1) * 4] = z;
    }

    // x batch addressing: this lane's GEMM column = (ts = lr>>1, seq = lr&1)
    const _Float16* xcol = x16 + (size_t)(bp * 2 + (lr & 1)) * T_ * IN_ + g * HG_;
    float*          orow = out + (size_t)b * T_ * IN_ + g * HG_ + jl;

    // prologue: load x B-frags for batch 0 (ts = lr>>1)
    half8 bx[4];
    {
        const _Float16* px = xcol + (size_t)(lr >> 1) * IN_;
#pragma unroll
        for (int kt = 0; kt < 4; ++kt) bx[kt] = *(const half8*)(px + kt * 32 + hi * 8);
    }

    __syncthreads();   // once, outside the loop

#define REC_STEP(S)                                                                \
    do {                                                                           \
        const int pb = (S) & 1;                                                    \
        /* 1. h B-frags */                                                         \
        const half8 bf0 = *(const half8*)&hmem[pb][lr * 128 + (( 0 + hi) ^ (lr & 7)) * 8]; \
        const half8 bf1 = *(const half8*)&hmem[pb][lr * 128 + (( 4 + hi) ^ (lr & 7)) * 8]; \
        const half8 bf2 = *(const half8*)&hmem[pb][lr * 128 + (( 8 + hi) ^ (lr & 7)) * 8]; \
        const half8 bf3 = *(const half8*)&hmem[pb][lr * 128 + ((12 + hi) ^ (lr & 7)) * 8]; \
        /* 2. xa for this step from xmem (same-wave data; lgkm only) */            \
        const int xc = (S) * 2 + sq;                                               \
        const f32x4 xa0 = *(const f32x4*)&xmem[xc][      jl];                      \
        const f32x4 xa1 = *(const f32x4*)&xmem[xc][128 + jl];                      \
        const f32x4 xa2 = *(const f32x4*)&xmem[xc][256 + jl];                      \
        /* 3. h-MFMA, 2+2 split; r,z chains seeded with xa; n with S_N*bh_n */     \
        f32x4 h0a = xa0, h1a = xa1, h2a = bhn_s;                                   \
        f32x4 h0b = (f32x4){0.f,0.f,0.f,0.f}, h1b = h0b, h2b = h0b;                \
        h0a = MFMA16(aH[0][0], bf0, h0a);                                          \
        h1a = MFMA16(aH[1][0], bf0, h1a);                                          \
        h2a = MFMA16(aH[2][0], bf0, h2a);                                          \
        h0b = MFMA16(aH[0][2], bf2, h0b);                                          \
        h1b = MFMA16(aH[1][2], bf2, h1b);                                          \
        h2b = MFMA16(aH[2][2], bf2, h2b);                                          \
        h0a = MFMA16(aH[0][1], bf1, h0a);                                          \
        h1a = MFMA16(aH[1][1], bf1, h1a);                                          \
        h2a = MFMA16(aH[2][1], bf1, h2a);                                          \
        h0b = MFMA16(aH[0][3], bf3, h0b);                                          \
        h1b = MFMA16(aH[1][3], bf3, h1b);                                          \
        h2b = MFMA16(aH[2][3], bf3, h2b);                                          \
        const f32x4 ar = h0a + h0b;   /* S_RZ*(xr+hr+b) */                         \
        const f32x4 az = h1a + h1b;   /* S_RZ*(xz+hz+b) */                         \
        const f32x4 an = h2a + h2b;   /* S_N*(hn+bh_n) */                          \
        /* 4. lane-local gates */                                                  \
        f32x4 hnew;                                                                \
        _Pragma("unroll")                                                          \
        for (int r = 0; r < 4; ++r) {                                              \
            const float rg = __builtin_amdgcn_rcpf(1.f + __builtin_amdgcn_exp2f(ar[r])); \
            const float zg = __builtin_amdgcn_rcpf(1.f + __builtin_amdgcn_exp2f(az[r])); \
            const float pre = xa2[r] + rg * an[r];                                 \
            const float th  = __builtin_fmaf(2.f,                                  \
                __builtin_amdgcn_rcpf(1.f + __builtin_amdgcn_exp2f(pre)), -1.f);   \
            hnew[r] = __builtin_fmaf(zg, hreg[r] - th, th);                        \
        }                                                                          \
        hreg = hnew;                                                               \
        /* 5. write h (swizzled), lds-only barrier */                              \
        {                                                                          \
            half4 hh;                                                              \
            hh[0]=(_Float16)hnew[0]; hh[1]=(_Float16)hnew[1];                      \
            hh[2]=(_Float16)hnew[2]; hh[3]=(_Float16)hnew[3];                      \
            *(half4*)&hmem[pb ^ 1][lr * 128 + gi * 8 + (hi & 1) * 4] = hh;         \
        }                                                                          \
        barrier_lds_only();                                                        \
        /* 6. masked out store (cols >=2 are duplicates for the h-path) */         \
        if (lr < 2) *(f32x4*)(orow + (size_t)(t0 + (S)) * IN_) = hnew;             \
    } while (0)

    for (int t0 = 0; t0 < T_; t0 += 8) {
        // ---- batch x-GEMM: xa for 8 timesteps x 2 seqs (cols all real) ----
        {
            f32x4 d0 = s0, d1 = s1, d2 = s2;
#pragma unroll
            for (int kt = 0; kt < 4; ++kt) {
                d0 = MFMA16(aI[0][kt], bx[kt], d0);
                d1 = MFMA16(aI[1][kt], bx[kt], d1);
                d2 = MFMA16(aI[2][kt], bx[kt], d2);
            }
            // D: lane (lr,hi) holds xa[j = p*128 + w*16 + hi*4 + r][col = lr]
            *(f32x4*)&xmem[lr][      w * 16 + hi * 4] = d0;
            *(f32x4*)&xmem[lr][128 + w * 16 + hi * 4] = d1;
            *(f32x4*)&xmem[lr][256 + w * 16 + hi * 4] = d2;
            // issue next batch's x loads (8 steps of flight time)
            int tn = t0 + 8 + (lr >> 1); if (tn > T_ - 1) tn = T_ - 1;
            const _Float16* px = xcol + (size_t)tn * IN_;
#pragma unroll
            for (int kt = 0; kt < 4; ++kt) bx[kt] = *(const half8*)(px + kt * 32 + hi * 8);
        }
        // ---- 8 recurrence steps (4 on the tail batch: 500 = 62*8 + 4) ----
        REC_STEP(0); REC_STEP(1); REC_STEP(2); REC_STEP(3);
        if (t0 + 4 < T_) {
            REC_STEP(4); REC_STEP(5); REC_STEP(6); REC_STEP(7);
        }
    }
#undef REC_STEP
}

// ---------------------------------------------------------------------------
extern "C" void kernel_launch(void* const* d_in, const int* in_sizes, int n_in,
                              void* d_out, int out_size, void* d_ws, size_t ws_size,
                              hipStream_t stream) {
    (void)in_sizes; (void)n_in; (void)out_size; (void)ws_size;
    const float* x   = (const float*)d_in[0];
    const float* Wih = (const float*)d_in[1];
    const float* Whh = (const float*)d_in[2];
    const float* bih = (const float*)d_in[3];
    const float* bhh = (const float*)d_in[4];
    float* out = (float*)d_out;

    _Float16* x16 = (_Float16*)d_ws;    // 65.5 MB

    cvt_x<<<4096, 256, 0, stream>>>(x, x16);
    gru_fused<<<256, 512, 0, stream>>>(Wih, Whh, bih, bhh, x16, out);
}

// Round 15
// 267.944 us; speedup vs baseline: 2.9481x; 1.3588x over previous
//
#include <hip/hip_runtime.h>
#include <math.h>

#define B_   64
#define T_   500
#define IN_  1024
#define G_   8
#define HG_  128
#define J3_  384   // 3*HG

typedef _Float16 half8 __attribute__((ext_vector_type(8)));
typedef _Float16 half4 __attribute__((ext_vector_type(4)));
typedef float    f32x4 __attribute__((ext_vector_type(4)));

// sigmoid(a) = rcp(1 + exp2(S_RZ*a)); tanh(p) = 2*rcp(1+exp2(S_N*p))-1.
// Scales folded into the f16 weights and bias seeds (no muls in gates).
#define S_RZ (-1.44269504f)
#define S_N  (-2.88539008f)

static __device__ __forceinline__ half8 cvt_half8_s(const float* p, float s) {
    const float4 a = *(const float4*)p;
    const float4 b = *(const float4*)(p + 4);
    half8 h;
    h[0]=(_Float16)(a.x*s); h[1]=(_Float16)(a.y*s); h[2]=(_Float16)(a.z*s); h[3]=(_Float16)(a.w*s);
    h[4]=(_Float16)(b.x*s); h[5]=(_Float16)(b.y*s); h[6]=(_Float16)(b.z*s); h[7]=(_Float16)(b.w*s);
    return h;
}

// opaque reg-to-reg barrier: prevents rematerialization of loop-invariant state
static __device__ __forceinline__ void pin_frag(half8& h) {
    f32x4 t = __builtin_bit_cast(f32x4, h);
    float a = t[0], b = t[1], c = t[2], d = t[3];
    asm volatile("" : "+v"(a), "+v"(b), "+v"(c), "+v"(d));
    t[0] = a; t[1] = b; t[2] = c; t[3] = d;
    h = __builtin_bit_cast(half8, t);
}
static __device__ __forceinline__ void pin_f32x4(f32x4& v) {
    float a = v[0], b = v[1], c = v[2], d = v[3];
    asm volatile("" : "+v"(a), "+v"(b), "+v"(c), "+v"(d));
    v[0] = a; v[1] = b; v[2] = c; v[3] = d;
}

// LDS-only barrier: orders ds ops across the workgroup WITHOUT draining vmcnt.
static __device__ __forceinline__ void barrier_lds_only() {
    asm volatile("s_waitcnt lgkmcnt(0)\n\ts_barrier" ::: "memory");
}

// per-lane select of one element from an f32x4 (constant indices only -> no
// scratch; the two rsel-masks are loop-invariant and get hoisted)
static __device__ __forceinline__ float sel4(f32x4 v, int rsel) {
    const float t0 = (rsel & 1) ? v[1] : v[0];
    const float t1 = (rsel & 1) ? v[3] : v[2];
    return (rsel & 2) ? t1 : t0;
}

#define MFMA16(A,Bv,C) __builtin_amdgcn_mfma_f32_16x16x32_f16((A),(Bv),(C),0,0,0)

// ---------------------------------------------------------------------------
// Kernel 0: cast x (fp32) -> x16 (f16), one-shot, memory-bound (~30 us).
// ---------------------------------------------------------------------------
__global__ __launch_bounds__(256)
void cvt_x(const float* __restrict__ x, _Float16* __restrict__ x16)
{
    const size_t n4 = (size_t)B_ * T_ * IN_ / 4;
    const size_t stride = (size_t)gridDim.x * 256;
    for (size_t i = (size_t)blockIdx.x * 256 + threadIdx.x; i < n4; i += stride) {
        const float4 v = ((const float4*)x)[i];
        half4 h;
        h[0] = (_Float16)v.x; h[1] = (_Float16)v.y;
        h[2] = (_Float16)v.z; h[3] = (_Float16)v.w;
        ((half4*)x16)[i] = h;
    }
}

// ---------------------------------------------------------------------------
// Kernel 1 (structure G6 = G5 + gate DEDUP + broadcast hmem):
// 256 blocks x 512 thr (8 waves), 2 real seqs/block.
// Round-14 PMC: VALU ~743cy/SIMD/step > MFMA 466cy; 8x-duplicated gate
// trans (24/wave @ ~8cy) was ~384cy of it; hmem col-major (256B stride)
// caused ~8-way bank conflicts (2.36e7).
// Fixes: (a) lane owns ONE r (rsel=(lr>>1)&3): 6 trans/wave (4x less), D-frag
// element picked by loop-invariant cndmask selects; (b) hmem -> h16[2][2][128]
// seq-indexed: B-frag reads are broadcasts (free), writes scalar (lr<8);
// (c) no 2+2 split (xa rides C-in; no f32x4 adds).
// x-projection stays timestep-batched (16 cols = 8 ts x 2 seqs, 1.5/step).
// ---------------------------------------------------------------------------
__global__ __launch_bounds__(512, 1)
void gru_fused(const float* __restrict__ Wih, const float* __restrict__ Whh,
               const float* __restrict__ bih, const float* __restrict__ bhh,
               const _Float16* __restrict__ x16, float* __restrict__ out)
{
    const int tid  = threadIdx.x;
    const int lane = tid & 63;
    const int w    = tid >> 6;        // wave 0..7 == j-tile
    const int lr   = lane & 15;       // MFMA col
    const int hi   = lane >> 4;       // 0..3
    const int blk  = blockIdx.x;      // 0..255
    const int g    = blk & 7;         // == XCD
    const int bp   = blk >> 3;        // 0..31
    const int sq   = lr & 1;          // seq parity (h-path col -> seq)
    const int rsel = (lr >> 1) & 3;   // the ONE r this lane owns
    const int jl   = w * 16 + hi * 4;
    const int jown = jl + rsel;       // owned j
    const int bown = bp * 2 + sq;     // owned sequence

    __shared__ _Float16 h16[2][2][HG_];      // 1 KB: [buf][seq][j]
    __shared__ float    xmem[16][392];       // 24.5 KB: [col = ts*2+seq][gate*128 + j]

    // ---- persistent pinned fragments, gate scales folded in ----
    half8 aI[3][4], aH[3][4];
#pragma unroll
    for (int p = 0; p < 3; ++p)
#pragma unroll
        for (int kt = 0; kt < 4; ++kt) {
            const size_t roff = (size_t)(g * J3_ + p * 128 + w * 16 + lr) * HG_
                              + kt * 32 + hi * 8;
            const float s = (p == 2) ? S_N : S_RZ;
            aI[p][kt] = cvt_half8_s(Wih + roff, s);  pin_frag(aI[p][kt]);
            aH[p][kt] = cvt_half8_s(Whh + roff, s);  pin_frag(aH[p][kt]);
        }

    // ---- bias seeds (scaled): r,z fold bih+bhh into x-GEMM; n splits ----
    const float* bi = bih + g * J3_;
    const float* bh = bhh + g * J3_;
    f32x4 s0 = (*(const f32x4*)(bi + jl)       + *(const f32x4*)(bh + jl))       * S_RZ;
    f32x4 s1 = (*(const f32x4*)(bi + 128 + jl) + *(const f32x4*)(bh + 128 + jl)) * S_RZ;
    f32x4 s2 = (*(const f32x4*)(bi + 256 + jl)) * S_N;
    f32x4 bhn_s = (*(const f32x4*)(bh + 256 + jl)) * S_N;
    pin_f32x4(s0); pin_f32x4(s1); pin_f32x4(s2); pin_f32x4(bhn_s);

    // ---- h = 0 init ----
    float hreg = 0.f;                 // own (seq, j) hidden state
    if (tid < 256) h16[0][tid >> 7][tid & 127] = (_Float16)0.f;

    // x batch addressing: this lane's GEMM column = (ts = lr>>1, seq = lr&1)
    const _Float16* xcol = x16 + (size_t)(bp * 2 + (lr & 1)) * T_ * IN_ + g * HG_;
    float*          oown = out + (size_t)bown * T_ * IN_ + g * HG_ + jown;

    // prologue: load x B-frags for batch 0 (ts = lr>>1)
    half8 bx[4];
    {
        const _Float16* px = xcol + (size_t)(lr >> 1) * IN_;
#pragma unroll
        for (int kt = 0; kt < 4; ++kt) bx[kt] = *(const half8*)(px + kt * 32 + hi * 8);
    }

    __syncthreads();   // once, outside the loop

#define REC_STEP(S)                                                                \
    do {                                                                           \
        const int pb = (S) & 1;                                                    \
        /* 1. h B-frags: broadcast reads (8 distinct addrs, 2-way alias) */        \
        const _Float16* hsrc = &h16[pb][sq][0];                                    \
        const half8 bf0 = *(const half8*)(hsrc +  0 + hi * 8);                     \
        const half8 bf1 = *(const half8*)(hsrc + 32 + hi * 8);                     \
        const half8 bf2 = *(const half8*)(hsrc + 64 + hi * 8);                     \
        const half8 bf3 = *(const half8*)(hsrc + 96 + hi * 8);                     \
        /* 2. xa for this step from xmem (same-wave data; lgkm only) */            \
        const int xc = (S) * 2 + sq;                                               \
        const f32x4 xa0 = *(const f32x4*)&xmem[xc][      jl];                      \
        const f32x4 xa1 = *(const f32x4*)&xmem[xc][128 + jl];                      \
        const f32x4 xa2 = *(const f32x4*)&xmem[xc][256 + jl];                      \
        /* 3. h-MFMA: 3 independent 4-chains; xa / S_N*bh_n ride C-in */           \
        f32x4 h0 = xa0, h1 = xa1, h2 = bhn_s;                                      \
        h0 = MFMA16(aH[0][0], bf0, h0);                                            \
        h1 = MFMA16(aH[1][0], bf0, h1);                                            \
        h2 = MFMA16(aH[2][0], bf0, h2);                                            \
        h0 = MFMA16(aH[0][1], bf1, h0);                                            \
        h1 = MFMA16(aH[1][1], bf1, h1);                                            \
        h2 = MFMA16(aH[2][1], bf1, h2);                                            \
        h0 = MFMA16(aH[0][2], bf2, h0);                                            \
        h1 = MFMA16(aH[1][2], bf2, h1);                                            \
        h2 = MFMA16(aH[2][2], bf2, h2);                                            \
        h0 = MFMA16(aH[0][3], bf3, h0);                                            \
        h1 = MFMA16(aH[1][3], bf3, h1);                                            \
        h2 = MFMA16(aH[2][3], bf3, h2);                                            \
        /* 4. gates for the ONE owned (seq, j): 6 trans per wave */                \
        const float ar = sel4(h0, rsel);    /* S_RZ*(xr+hr+b) */                   \
        const float az = sel4(h1, rsel);    /* S_RZ*(xz+hz+b) */                   \
        const float an = sel4(h2, rsel);    /* S_N*(hn+bh_n) */                    \
        const float xn = sel4(xa2, rsel);   /* S_N*(xn+bi_n) */                    \
        const float rg = __builtin_amdgcn_rcpf(1.f + __builtin_amdgcn_exp2f(ar));  \
        const float zg = __builtin_amdgcn_rcpf(1.f + __builtin_amdgcn_exp2f(az));  \
        const float pre = xn + rg * an;                                            \
        const float th  = __builtin_fmaf(2.f,                                      \
            __builtin_amdgcn_rcpf(1.f + __builtin_amdgcn_exp2f(pre)), -1.f);       \
        const float hnew = __builtin_fmaf(zg, hreg - th, th);                      \
        hreg = hnew;                                                               \
        /* 5. write h (one writer per value) + out store */                        \
        if (lr < 8) {                                                              \
            h16[pb ^ 1][sq][jown] = (_Float16)hnew;                                \
            oown[(size_t)(t0 + (S)) * IN_] = hnew;                                 \
        }                                                                          \
        barrier_lds_only();                                                        \
    } while (0)

    for (int t0 = 0; t0 < T_; t0 += 8) {
        // ---- batch x-GEMM: xa for 8 timesteps x 2 seqs (cols all real) ----
        {
            f32x4 d0 = s0, d1 = s1, d2 = s2;
#pragma unroll
            for (int kt = 0; kt < 4; ++kt) {
                d0 = MFMA16(aI[0][kt], bx[kt], d0);
                d1 = MFMA16(aI[1][kt], bx[kt], d1);
                d2 = MFMA16(aI[2][kt], bx[kt], d2);
            }
            // D: lane (lr,hi) holds xa[j = p*128 + w*16 + hi*4 + r][col = lr]
            *(f32x4*)&xmem[lr][      w * 16 + hi * 4] = d0;
            *(f32x4*)&xmem[lr][128 + w * 16 + hi * 4] = d1;
            *(f32x4*)&xmem[lr][256 + w * 16 + hi * 4] = d2;
            // issue next batch's x loads (8 steps of flight time)
            int tn = t0 + 8 + (lr >> 1); if (tn > T_ - 1) tn = T_ - 1;
            const _Float16* px = xcol + (size_t)tn * IN_;
#pragma unroll
            for (int kt = 0; kt < 4; ++kt) bx[kt] = *(const half8*)(px + kt * 32 + hi * 8);
        }
        // ---- 8 recurrence steps (4 on the tail batch: 500 = 62*8 + 4) ----
        REC_STEP(0); REC_STEP(1); REC_STEP(2); REC_STEP(3);
        if (t0 + 4 < T_) {
            REC_STEP(4); REC_STEP(5); REC_STEP(6); REC_STEP(7);
        }
    }
#undef REC_STEP
}

// ---------------------------------------------------------------------------
extern "C" void kernel_launch(void* const* d_in, const int* in_sizes, int n_in,
                              void* d_out, int out_size, void* d_ws, size_t ws_size,
                              hipStream_t stream) {
    (void)in_sizes; (void)n_in; (void)out_size; (void)ws_size;
    const float* x   = (const float*)d_in[0];
    const float* Wih = (const float*)d_in[1];
    const float* Whh = (const float*)d_in[2];
    const float* bih = (const float*)d_in[3];
    const float* bhh = (const float*)d_in[4];
    float* out = (float*)d_out;

    _Float16* x16 = (_Float16*)d_ws;    // 65.5 MB

    cvt_x<<<4096, 256, 0, stream>>>(x, x16);
    gru_fused<<<256, 512, 0, stream>>>(Wih, Whh, bih, bhh, x16, out);
}

// Round 16
// 260.150 us; speedup vs baseline: 3.0365x; 1.0300x over previous
//
#include <hip/hip_runtime.h>
#include <math.h>

#define B_   64
#define T_   500
#define IN_  1024
#define G_   8
#define HG_  128
#define J3_  384   // 3*HG

typedef _Float16 half8 __attribute__((ext_vector_type(8)));
typedef _Float16 half4 __attribute__((ext_vector_type(4)));
typedef float    f32x4 __attribute__((ext_vector_type(4)));

// sigmoid(a) = rcp(1 + exp2(S_RZ*a)); tanh(p) = 2*rcp(1+exp2(S_N*p))-1.
// Scales folded into the f16 weights and bias seeds (no muls in gates).
#define S_RZ (-1.44269504f)
#define S_N  (-2.88539008f)

static __device__ __forceinline__ half8 cvt_half8_s(const float* p, float s) {
    const float4 a = *(const float4*)p;
    const float4 b = *(const float4*)(p + 4);
    half8 h;
    h[0]=(_Float16)(a.x*s); h[1]=(_Float16)(a.y*s); h[2]=(_Float16)(a.z*s); h[3]=(_Float16)(a.w*s);
    h[4]=(_Float16)(b.x*s); h[5]=(_Float16)(b.y*s); h[6]=(_Float16)(b.z*s); h[7]=(_Float16)(b.w*s);
    return h;
}

// opaque reg-to-reg barrier: prevents rematerialization of loop-invariant state
static __device__ __forceinline__ void pin_frag(half8& h) {
    f32x4 t = __builtin_bit_cast(f32x4, h);
    float a = t[0], b = t[1], c = t[2], d = t[3];
    asm volatile("" : "+v"(a), "+v"(b), "+v"(c), "+v"(d));
    t[0] = a; t[1] = b; t[2] = c; t[3] = d;
    h = __builtin_bit_cast(half8, t);
}
static __device__ __forceinline__ void pin_f32x4(f32x4& v) {
    float a = v[0], b = v[1], c = v[2], d = v[3];
    asm volatile("" : "+v"(a), "+v"(b), "+v"(c), "+v"(d));
    v[0] = a; v[1] = b; v[2] = c; v[3] = d;
}

// LDS-only barrier: orders ds ops across the workgroup WITHOUT draining vmcnt.
static __device__ __forceinline__ void barrier_lds_only() {
    asm volatile("s_waitcnt lgkmcnt(0)\n\ts_barrier" ::: "memory");
}

// per-lane select of one element from an f32x4 (constant indices only; the
// two rsel-masks are loop-invariant and hoisted)
static __device__ __forceinline__ float sel4(f32x4 v, int rsel) {
    const float t0 = (rsel & 1) ? v[1] : v[0];
    const float t1 = (rsel & 1) ? v[3] : v[2];
    return (rsel & 2) ? t1 : t0;
}

#define MFMA16(A,Bv,C) __builtin_amdgcn_mfma_f32_16x16x32_f16((A),(Bv),(C),0,0,0)

// ---------------------------------------------------------------------------
// Kernel 0: cast x (fp32) -> x16 (f16), one-shot, memory-bound (~30 us).
// ---------------------------------------------------------------------------
__global__ __launch_bounds__(256)
void cvt_x(const float* __restrict__ x, _Float16* __restrict__ x16)
{
    const size_t n4 = (size_t)B_ * T_ * IN_ / 4;
    const size_t stride = (size_t)gridDim.x * 256;
    for (size_t i = (size_t)blockIdx.x * 256 + threadIdx.x; i < n4; i += stride) {
        const float4 v = ((const float4*)x)[i];
        half4 h;
        h[0] = (_Float16)v.x; h[1] = (_Float16)v.y;
        h[2] = (_Float16)v.z; h[3] = (_Float16)v.w;
        ((half4*)x16)[i] = h;
    }
}

// ---------------------------------------------------------------------------
// Kernel 1 (structure G7 = G6 + spread x-GEMM + xa prefetch):
// 256 blocks x 512 thr (8 waves), 2 real seqs/block.
// Round-15 PMC: step ~1170cy = MFMA 428 + VALU 384 + ~360 serial slop.
// This round shaves the slop: (a) the 12-MFMA x-batch burst (once/8 steps)
// is spread 3-per-step over steps 0-3 (chain kt=S) - fills the post-barrier
// bf-read latency window; xmem double-buffered (batch t0+8 computed during
// iteration t0). (b) next step's xa ds_reads prefetched into registers
// during the current step (same-wave xmem data; mid-step read safe).
// (c) bx reload at S==3 -> 12+ steps of flight.
// ---------------------------------------------------------------------------
__global__ __launch_bounds__(512, 1)
void gru_fused(const float* __restrict__ Wih, const float* __restrict__ Whh,
               const float* __restrict__ bih, const float* __restrict__ bhh,
               const _Float16* __restrict__ x16, float* __restrict__ out)
{
    const int tid  = threadIdx.x;
    const int lane = tid & 63;
    const int w    = tid >> 6;        // wave 0..7 == j-tile
    const int lr   = lane & 15;       // MFMA col
    const int hi   = lane >> 4;       // 0..3
    const int blk  = blockIdx.x;      // 0..255
    const int g    = blk & 7;         // == XCD
    const int bp   = blk >> 3;        // 0..31
    const int sq   = lr & 1;          // seq parity
    const int rsel = (lr >> 1) & 3;   // the ONE r this lane owns
    const int jl   = w * 16 + hi * 4;
    const int jown = jl + rsel;       // owned j
    const int bown = bp * 2 + sq;     // owned sequence

    __shared__ _Float16 h16[2][2][HG_];      // 1 KB: [buf][seq][j]
    __shared__ float    xmem[2][16][392];    // 49 KB: [xbuf][col=ts*2+seq][gate*128+j]

    // ---- persistent pinned fragments, gate scales folded in ----
    half8 aI[3][4], aH[3][4];
#pragma unroll
    for (int p = 0; p < 3; ++p)
#pragma unroll
        for (int kt = 0; kt < 4; ++kt) {
            const size_t roff = (size_t)(g * J3_ + p * 128 + w * 16 + lr) * HG_
                              + kt * 32 + hi * 8;
            const float s = (p == 2) ? S_N : S_RZ;
            aI[p][kt] = cvt_half8_s(Wih + roff, s);  pin_frag(aI[p][kt]);
            aH[p][kt] = cvt_half8_s(Whh + roff, s);  pin_frag(aH[p][kt]);
        }

    // ---- bias seeds (scaled): r,z fold bih+bhh into x-GEMM; n splits ----
    const float* bi = bih + g * J3_;
    const float* bh = bhh + g * J3_;
    f32x4 s0 = (*(const f32x4*)(bi + jl)       + *(const f32x4*)(bh + jl))       * S_RZ;
    f32x4 s1 = (*(const f32x4*)(bi + 128 + jl) + *(const f32x4*)(bh + 128 + jl)) * S_RZ;
    f32x4 s2 = (*(const f32x4*)(bi + 256 + jl)) * S_N;
    f32x4 bhn_s = (*(const f32x4*)(bh + 256 + jl)) * S_N;
    pin_f32x4(s0); pin_f32x4(s1); pin_f32x4(s2); pin_f32x4(bhn_s);

    // ---- h = 0 init ----
    float hreg = 0.f;
    if (tid < 256) h16[0][tid >> 7][tid & 127] = (_Float16)0.f;

    // x addressing: this lane's GEMM column = (ts = lr>>1, seq = lr&1)
    const _Float16* xcol = x16 + (size_t)(bp * 2 + (lr & 1)) * T_ * IN_ + g * HG_;
    float*          oown = out + (size_t)bown * T_ * IN_ + g * HG_ + jown;

    // ---- prologue: batch 0 (steps 0..7) burst into xmem[0] ----
    half8 bx[4];
    {
        const _Float16* px = xcol + (size_t)(lr >> 1) * IN_;
#pragma unroll
        for (int kt = 0; kt < 4; ++kt) bx[kt] = *(const half8*)(px + kt * 32 + hi * 8);
    }
    {
        f32x4 d0 = s0, d1 = s1, d2 = s2;
#pragma unroll
        for (int kt = 0; kt < 4; ++kt) {
            d0 = MFMA16(aI[0][kt], bx[kt], d0);
            d1 = MFMA16(aI[1][kt], bx[kt], d1);
            d2 = MFMA16(aI[2][kt], bx[kt], d2);
        }
        *(f32x4*)&xmem[0][lr][      w * 16 + hi * 4] = d0;
        *(f32x4*)&xmem[0][lr][128 + w * 16 + hi * 4] = d1;
        *(f32x4*)&xmem[0][lr][256 + w * 16 + hi * 4] = d2;
    }
    // load bx for batch 1 (steps 8..15)
    {
        int tn = 8 + (lr >> 1); if (tn > T_ - 1) tn = T_ - 1;
        const _Float16* px = xcol + (size_t)tn * IN_;
#pragma unroll
        for (int kt = 0; kt < 4; ++kt) bx[kt] = *(const half8*)(px + kt * 32 + hi * 8);
    }
    // prefetch xa for step 0 (same-wave xmem data; no barrier needed)
    f32x4 pxa0, pxa1, pxa2;
    {
        const int xc = sq;
        pxa0 = *(const f32x4*)&xmem[0][xc][      jl];
        pxa1 = *(const f32x4*)&xmem[0][xc][128 + jl];
        pxa2 = *(const f32x4*)&xmem[0][xc][256 + jl];
    }
    // rolling x-batch accumulators (live across steps 0..3)
    f32x4 d0, d1, d2;

    __syncthreads();   // once, outside the loop

#define REC_STEP(S)                                                                \
    do {                                                                           \
        const int pb = (S) & 1;                                                    \
        /* 1. h B-frags: broadcast reads */                                        \
        const _Float16* hsrc = &h16[pb][sq][0];                                    \
        const half8 bf0 = *(const half8*)(hsrc +  0 + hi * 8);                     \
        const half8 bf1 = *(const half8*)(hsrc + 32 + hi * 8);                     \
        const half8 bf2 = *(const half8*)(hsrc + 64 + hi * 8);                     \
        const half8 bf3 = *(const half8*)(hsrc + 96 + hi * 8);                     \
        /* 2. x-GEMM slice for next batch (kt = S, steps 0..3): fills the */       \
        /*    bf-read latency window; depends only on long-resident bx */          \
        if ((S) == 0) { d0 = s0; d1 = s1; d2 = s2; }                               \
        if ((S) < 4) {                                                             \
            d0 = MFMA16(aI[0][(S) & 3], bx[(S) & 3], d0);                          \
            d1 = MFMA16(aI[1][(S) & 3], bx[(S) & 3], d1);                          \
            d2 = MFMA16(aI[2][(S) & 3], bx[(S) & 3], d2);                          \
        }                                                                          \
        /* 3. h-MFMA: 3 chains; prefetched xa / S_N*bh_n ride C-in */              \
        f32x4 h0 = pxa0, h1 = pxa1, h2 = bhn_s;                                    \
        h0 = MFMA16(aH[0][0], bf0, h0);                                            \
        h1 = MFMA16(aH[1][0], bf0, h1);                                            \
        h2 = MFMA16(aH[2][0], bf0, h2);                                            \
        h0 = MFMA16(aH[0][1], bf1, h0);                                            \
        h1 = MFMA16(aH[1][1], bf1, h1);                                            \
        h2 = MFMA16(aH[2][1], bf1, h2);                                            \
        h0 = MFMA16(aH[0][2], bf2, h0);                                            \
        h1 = MFMA16(aH[1][2], bf2, h1);                                            \
        h2 = MFMA16(aH[2][2], bf2, h2);                                            \
        h0 = MFMA16(aH[0][3], bf3, h0);                                            \
        h1 = MFMA16(aH[1][3], bf3, h1);                                            \
        h2 = MFMA16(aH[2][3], bf3, h2);                                            \
        /* 4. finish next batch at S==3: write xmem[xb^1], reload bx */            \
        if ((S) == 3) {                                                            \
            *(f32x4*)&xmem[xb ^ 1][lr][      w * 16 + hi * 4] = d0;                \
            *(f32x4*)&xmem[xb ^ 1][lr][128 + w * 16 + hi * 4] = d1;                \
            *(f32x4*)&xmem[xb ^ 1][lr][256 + w * 16 + hi * 4] = d2;                \
            int tn = t0 + 16 + (lr >> 1); if (tn > T_ - 1) tn = T_ - 1;            \
            const _Float16* px = xcol + (size_t)tn * IN_;                          \
            bx[0] = *(const half8*)(px +  0 + hi * 8);                             \
            bx[1] = *(const half8*)(px + 32 + hi * 8);                             \
            bx[2] = *(const half8*)(px + 64 + hi * 8);                             \
            bx[3] = *(const half8*)(px + 96 + hi * 8);                             \
        }                                                                          \
        /* 5. prefetch xa for step S+1 (same-wave xmem data) */                    \
        {                                                                          \
            const int nxb = ((S) == 7) ? (xb ^ 1) : xb;                            \
            const int nxc = (((S) + 1) & 7) * 2 + sq;                              \
            pxa0 = *(const f32x4*)&xmem[nxb][nxc][      jl];                       \
            pxa1 = *(const f32x4*)&xmem[nxb][nxc][128 + jl];                       \
            pxa2 = *(const f32x4*)&xmem[nxb][nxc][256 + jl];                       \
        }                                                                          \
        /* 6. gates for the ONE owned (seq, j): 6 trans per wave */                \
        const float ar = sel4(h0, rsel);                                           \
        const float az = sel4(h1, rsel);                                           \
        const float an = sel4(h2, rsel);                                           \
        const float xn = xn_cur;                                                   \
        const float rg = __builtin_amdgcn_rcpf(1.f + __builtin_amdgcn_exp2f(ar));  \
        const float zg = __builtin_amdgcn_rcpf(1.f + __builtin_amdgcn_exp2f(az));  \
        const float pre = xn + rg * an;                                            \
        const float th  = __builtin_fmaf(2.f,                                      \
            __builtin_amdgcn_rcpf(1.f + __builtin_amdgcn_exp2f(pre)), -1.f);       \
        const float hnew = __builtin_fmaf(zg, hreg - th, th);                      \
        hreg = hnew;                                                               \
        /* 7. write h (one writer per value) + out store */                        \
        if (lr < 8) {                                                              \
            h16[pb ^ 1][sq][jown] = (_Float16)hnew;                                \
            oown[(size_t)(t0 + (S)) * IN_] = hnew;                                 \
        }                                                                          \
        barrier_lds_only();                                                        \
    } while (0)

    for (int t0 = 0; t0 < T_; t0 += 8) {
        const int xb = (t0 >> 3) & 1;
        // xn for the current step must be captured BEFORE pxa2 is overwritten
        // by the prefetch; sel4 it at step entry.
        {
            float xn_cur = sel4(pxa2, rsel);
            REC_STEP(0);
        }
        { float xn_cur = sel4(pxa2, rsel); REC_STEP(1); }
        { float xn_cur = sel4(pxa2, rsel); REC_STEP(2); }
        { float xn_cur = sel4(pxa2, rsel); REC_STEP(3); }
        if (t0 + 4 < T_) {
            { float xn_cur = sel4(pxa2, rsel); REC_STEP(4); }
            { float xn_cur = sel4(pxa2, rsel); REC_STEP(5); }
            { float xn_cur = sel4(pxa2, rsel); REC_STEP(6); }
            { float xn_cur = sel4(pxa2, rsel); REC_STEP(7); }
        }
    }
#undef REC_STEP
}

// ---------------------------------------------------------------------------
extern "C" void kernel_launch(void* const* d_in, const int* in_sizes, int n_in,
                              void* d_out, int out_size, void* d_ws, size_t ws_size,
                              hipStream_t stream) {
    (void)in_sizes; (void)n_in; (void)out_size; (void)ws_size;
    const float* x   = (const float*)d_in[0];
    const float* Wih = (const float*)d_in[1];
    const float* Whh = (const float*)d_in[2];
    const float* bih = (const float*)d_in[3];
    const float* bhh = (const float*)d_in[4];
    float* out = (float*)d_out;

    _Float16* x16 = (_Float16*)d_ws;    // 65.5 MB

    cvt_x<<<4096, 256, 0, stream>>>(x, x16);
    gru_fused<<<256, 512, 0, stream>>>(Wih, Whh, bih, bhh, x16, out);
}